// Round 5
// baseline (110.573 us; speedup 1.0000x reference)
//
#include <hip/hip_runtime.h>

typedef unsigned int uint;

#define BATCH 8
#define HH 128
#define WW 128
#define CC 64
#define NPIX (BATCH * HH * WW)   // 131072
#define KK 9
#define BN_EPS 1e-3f

// ---- setup: transpose w1, pad w2 to 12 cols, fold b1 + BN ----
__global__ void setup_kernel(const float* __restrict__ w1,
                             const float* __restrict__ b1,
                             const float* __restrict__ gamma,
                             const float* __restrict__ beta,
                             const float* __restrict__ bn_mean,
                             const float* __restrict__ bn_var,
                             const float* __restrict__ w2,
                             const float* __restrict__ b2,
                             float* __restrict__ w1t,    // [64][64]: w1t[d][c] = w1[c][d]
                             float* __restrict__ w2p,    // [64][12] padded (cols 9..11 = 0)
                             float* __restrict__ scalef, // [64]
                             float* __restrict__ biasf,  // [64]
                             float* __restrict__ b2f)    // [9]
{
    int t = blockIdx.x * blockDim.x + threadIdx.x;
    int nt = gridDim.x * blockDim.x;
    for (int idx = t; idx < CC * CC; idx += nt) {
        int d = idx >> 6, c = idx & 63;
        w1t[idx] = w1[c * CC + d];
    }
    for (int idx = t; idx < CC * 12; idx += nt) {
        int d = idx / 12, k = idx - d * 12;
        w2p[idx] = (k < KK) ? w2[d * KK + k] : 0.f;
    }
    if (t < CC) {
        float s = gamma[t] * rsqrtf(bn_var[t] + BN_EPS);
        scalef[t] = s;
        biasf[t] = (b1[t] - bn_mean[t]) * s + beta[t];
    }
    if (t < KK) b2f[t] = b2[t];
}

// ---- kernel 1: kern generation. wave-independent, lane = d-channel ----
__global__ __launch_bounds__(256) void kern_gen(
    const float* __restrict__ x,
    const float* __restrict__ w1t,
    const float* __restrict__ w2p,
    const float* __restrict__ scalef,
    const float* __restrict__ biasf,
    const float* __restrict__ b2f,
    float* __restrict__ kout)    // [NPIX][9]
{
    __shared__ float hT[4][16][67];   // [wave][pixel][d], 67-stride -> 2-way banks (free)

    const int lane = threadIdx.x & 63;
    const int w = threadIdx.x >> 6;
    const int wu = __builtin_amdgcn_readfirstlane(w);
    const int p0 = blockIdx.x * 64 + wu * 16;      // uniform base pixel of this wave

    // ---- per-lane weights (loaded once; L1-resident after first wave) ----
    float wreg[CC];
    {
        const float4* wrow = (const float4*)(w1t + lane * CC);
#pragma unroll
        for (int f = 0; f < 16; ++f) {
            float4 v = wrow[f];
            wreg[4 * f + 0] = v.x; wreg[4 * f + 1] = v.y;
            wreg[4 * f + 2] = v.z; wreg[4 * f + 3] = v.w;
        }
    }
    const float sreg = scalef[lane];
    const float breg = biasf[lane];

    // ---- phase A: h[d=lane] for 16 pixels, x rows wave-uniform (s_load) ----
#pragma unroll 1
    for (int pp = 0; pp < 16; pp += 2) {
        const float4* xa = (const float4*)(x + (size_t)(p0 + pp) * CC);
        const float4* xb = (const float4*)(x + (size_t)(p0 + pp + 1) * CC);
        float ha = 0.f, hb = 0.f;
#pragma unroll
        for (int f = 0; f < 16; ++f) {
            float4 va = xa[f];
            float4 vb = xb[f];
            ha = fmaf(va.x, wreg[4 * f + 0], ha);
            ha = fmaf(va.y, wreg[4 * f + 1], ha);
            ha = fmaf(va.z, wreg[4 * f + 2], ha);
            ha = fmaf(va.w, wreg[4 * f + 3], ha);
            hb = fmaf(vb.x, wreg[4 * f + 0], hb);
            hb = fmaf(vb.y, wreg[4 * f + 1], hb);
            hb = fmaf(vb.z, wreg[4 * f + 2], hb);
            hb = fmaf(vb.w, wreg[4 * f + 3], hb);
        }
        hT[w][pp + 0][lane] = fmaxf(fmaf(ha, sreg, breg), 0.f);
        hT[w][pp + 1][lane] = fmaxf(fmaf(hb, sreg, breg), 0.f);
    }
    // same-wave handoff: only need lgkmcnt (compiler inserts); no barrier.

    // ---- phase B: lane = (px, dq); kern[9] partial over 16 d ----
    const int px = lane & 15;
    const int dq = lane >> 4;
    float kp[KK];
#pragma unroll
    for (int k = 0; k < KK; ++k) kp[k] = 0.f;

    const float* hrow = &hT[w][px][dq * 16];
    const float4* w2r = (const float4*)(w2p + dq * 16 * 12);
#pragma unroll
    for (int dd = 0; dd < 16; ++dd) {
        float hv = hrow[dd];
        float4 wa = w2r[dd * 3 + 0];
        float4 wb = w2r[dd * 3 + 1];
        float4 wc = w2r[dd * 3 + 2];
        kp[0] = fmaf(hv, wa.x, kp[0]);
        kp[1] = fmaf(hv, wa.y, kp[1]);
        kp[2] = fmaf(hv, wa.z, kp[2]);
        kp[3] = fmaf(hv, wa.w, kp[3]);
        kp[4] = fmaf(hv, wb.x, kp[4]);
        kp[5] = fmaf(hv, wb.y, kp[5]);
        kp[6] = fmaf(hv, wb.z, kp[6]);
        kp[7] = fmaf(hv, wb.w, kp[7]);
        kp[8] = fmaf(hv, wc.x, kp[8]);
    }
    // reduce across the 4 dq groups (lanes px, px+16, px+32, px+48)
#pragma unroll
    for (int k = 0; k < KK; ++k) {
        kp[k] += __shfl_xor(kp[k], 16, 64);
        kp[k] += __shfl_xor(kp[k], 32, 64);
    }
    if (dq == 0) {
        float* kr = kout + (size_t)(p0 + px) * KK;
#pragma unroll
        for (int k = 0; k < KK; ++k) kr[k] = kp[k] + b2f[k];
    }
}

// ---- kernel 2: involution. thread = (pixel, 16-ch quarter). LDS-free ----
__global__ __launch_bounds__(256) void invol2(
    const float* __restrict__ x,
    const float* __restrict__ kern_in,   // [NPIX][9]
    float* __restrict__ out)             // [NPIX][64]
{
    // XCD slab swizzle: 2048 blocks -> 8 slabs of 256 contiguous blocks
    int bid = blockIdx.x;
    bid = (bid & 7) * 256 + (bid >> 3);
    int T = bid * 256 + threadIdx.x;
    int p = T >> 2;
    int c0 = (T & 3) * 16;
    int b = p >> 14;
    int i = (p >> 7) & 127;
    int j = p & 127;

    float kern[KK];
    const float* kr = kern_in + (size_t)p * KK;
#pragma unroll
    for (int k = 0; k < KK; ++k) kern[k] = kr[k];

    float acc[16];
#pragma unroll
    for (int e = 0; e < 16; ++e) acc[e] = 0.f;

#pragma unroll
    for (int tap = 0; tap < KK; ++tap) {
        const int di = tap / 3 - 1, dj = tap % 3 - 1;
        int ii = i + di, jj = j + dj;
        bool valid = (ii >= 0) && (ii < HH) && (jj >= 0) && (jj < WW);
        float kv = valid ? kern[tap] : 0.f;
        int iic = min(max(ii, 0), HH - 1);
        int jjc = min(max(jj, 0), WW - 1);
        const float4* np = (const float4*)(x + (((size_t)b * HH + iic) * WW + jjc) * CC + c0);
#pragma unroll
        for (int f = 0; f < 4; ++f) {
            float4 v = np[f];
            acc[f * 4 + 0] = fmaf(kv, v.x, acc[f * 4 + 0]);
            acc[f * 4 + 1] = fmaf(kv, v.y, acc[f * 4 + 1]);
            acc[f * 4 + 2] = fmaf(kv, v.z, acc[f * 4 + 2]);
            acc[f * 4 + 3] = fmaf(kv, v.w, acc[f * 4 + 3]);
        }
    }

    float4* op = (float4*)(out + (size_t)p * CC + c0);
#pragma unroll
    for (int f = 0; f < 4; ++f)
        op[f] = make_float4(acc[f * 4 + 0], acc[f * 4 + 1], acc[f * 4 + 2], acc[f * 4 + 3]);
}

extern "C" void kernel_launch(void* const* d_in, const int* in_sizes, int n_in,
                              void* d_out, int out_size, void* d_ws, size_t ws_size,
                              hipStream_t stream) {
    const float* x       = (const float*)d_in[0];
    const float* w1      = (const float*)d_in[1];
    const float* b1      = (const float*)d_in[2];
    const float* gamma   = (const float*)d_in[3];
    const float* beta    = (const float*)d_in[4];
    const float* bn_mean = (const float*)d_in[5];
    const float* bn_var  = (const float*)d_in[6];
    const float* w2      = (const float*)d_in[7];
    const float* b2      = (const float*)d_in[8];

    float* w1t    = (float*)d_ws;          // 4096
    float* w2p    = w1t + CC * CC;         // 768
    float* scalef = w2p + CC * 12;         // 64
    float* biasf  = scalef + CC;           // 64
    float* b2f    = biasf + CC;            // 9

    float* out  = (float*)d_out;
    float* kout = out + (size_t)NPIX * CC;

    hipLaunchKernelGGL(setup_kernel, dim3(20), dim3(256), 0, stream,
                       w1, b1, gamma, beta, bn_mean, bn_var, w2, b2,
                       w1t, w2p, scalef, biasf, b2f);

    hipLaunchKernelGGL(kern_gen, dim3(NPIX / 64), dim3(256), 0, stream,
                       x, w1t, w2p, scalef, biasf, b2f, kout);

    hipLaunchKernelGGL(invol2, dim3(NPIX * 4 / 256), dim3(256), 0, stream,
                       x, kout, out);
}

// Round 6
// 59.817 us; speedup vs baseline: 1.8485x; 1.8485x over previous
//
#include <hip/hip_runtime.h>

typedef unsigned int uint;
typedef unsigned short ushort_t;
typedef __attribute__((ext_vector_type(8))) short short8v;   // 8 bf16 (4 VGPRs)
typedef __attribute__((ext_vector_type(4))) float f32x4;

#define BATCH 8
#define HH 128
#define WW 128
#define CC 64
#define NPIX (BATCH * HH * WW)   // 131072
#define KK 9
#define BN_EPS 1e-3f

__device__ __forceinline__ uint f2bfbits(float f) {
    uint u = __float_as_uint(f);
    return (u + 0x7fffu + ((u >> 16) & 1u)) >> 16;   // RNE, matches v_cvt_pk_bf16_f32
}

// ---- setup: w1 -> bf16 transposed [d][c]; pad w2 to 12; fold b1+BN ----
__global__ void setup_kernel(const float* __restrict__ w1,
                             const float* __restrict__ b1,
                             const float* __restrict__ gamma,
                             const float* __restrict__ beta,
                             const float* __restrict__ bn_mean,
                             const float* __restrict__ bn_var,
                             const float* __restrict__ w2,
                             const float* __restrict__ b2,
                             ushort_t* __restrict__ w1b,   // [64][64] bf16: w1b[d][c] = w1[c][d]
                             float* __restrict__ w2p,      // [64][12] padded
                             float* __restrict__ scalef,   // [64]
                             float* __restrict__ biasf,    // [64]
                             float* __restrict__ b2f)      // [9]
{
    int t = blockIdx.x * blockDim.x + threadIdx.x;
    int nt = gridDim.x * blockDim.x;
    for (int idx = t; idx < CC * CC; idx += nt) {
        int d = idx >> 6, c = idx & 63;
        w1b[idx] = (ushort_t)f2bfbits(w1[c * CC + d]);
    }
    for (int idx = t; idx < CC * 12; idx += nt) {
        int d = idx / 12, k = idx - d * 12;
        w2p[idx] = (k < KK) ? w2[d * KK + k] : 0.f;
    }
    if (t < CC) {
        float s = gamma[t] * rsqrtf(bn_var[t] + BN_EPS);
        scalef[t] = s;
        biasf[t] = (b1[t] - bn_mean[t]) * s + beta[t];
    }
    if (t < KK) b2f[t] = b2[t];
}

// ---- fused: stage -> MFMA GEMM1 -> VALU GEMM2 -> involution ----
__global__ __launch_bounds__(256) void invol_kernel(
    const float* __restrict__ x,
    const ushort_t* __restrict__ w1b,
    const float* __restrict__ w2p,
    const float* __restrict__ scalef,
    const float* __restrict__ biasf,
    const float* __restrict__ b2f,
    float* __restrict__ out,     // [NPIX][64]
    float* __restrict__ kout)    // [NPIX][9]
{
    __shared__ __align__(16) unsigned char smem[30208];
    ushort_t* xB = (ushort_t*)smem;              // [64][72] bf16 (pad -> conflict-free b128)
    float*    hS = (float*)(smem + 9216);        // [64][69] f32
    float*    kS = (float*)(smem + 26880);       // [64][13] f32

    const int t = threadIdx.x;
    int bid = blockIdx.x;
    bid = (bid & 7) * 256 + (bid >> 3);          // XCD slab swizzle (2048 = 8*256, bijective)
    const int p0 = bid * 64;

    // ---- phase 0: coalesced stage x -> bf16 LDS ----
#pragma unroll
    for (int r = 0; r < 4; ++r) {
        int idx = t + r * 256;
        int px = idx >> 4, c4 = idx & 15;
        float4 v = *(const float4*)(x + (size_t)(p0 + px) * CC + c4 * 4);
        uint2 pk;
        pk.x = f2bfbits(v.x) | (f2bfbits(v.y) << 16);
        pk.y = f2bfbits(v.z) | (f2bfbits(v.w) << 16);
        *(uint2*)(xB + px * 72 + c4 * 4) = pk;
    }
    __syncthreads();

    // ---- phase 1: GEMM1 h = relu(bn(x @ w1)) via MFMA; wave w = n-tile (d strip) ----
    {
        const int l = t & 63;
        const int w = __builtin_amdgcn_readfirstlane(t >> 6);
        const int lr = l & 15, lq = l >> 4;

        f32x4 acc[4];
#pragma unroll
        for (int m = 0; m < 4; ++m) acc[m] = (f32x4){0.f, 0.f, 0.f, 0.f};

#pragma unroll
        for (int ks = 0; ks < 2; ++ks) {
            // B-frag: lane = B[k=(lq)*8+j][n=lr] from w1b rows (B^T, K-contiguous)
            short8v bfrag = *(const short8v*)(w1b + (w * 16 + lr) * CC + ks * 32 + lq * 8);
#pragma unroll
            for (int m = 0; m < 4; ++m) {
                // A-frag: lane = A[row=lr][k=lq*8+j] from xB rows
                short8v afrag = *(const short8v*)(xB + (m * 16 + lr) * 72 + ks * 32 + lq * 8);
                acc[m] = __builtin_amdgcn_mfma_f32_16x16x32_bf16(afrag, bfrag, acc[m], 0, 0, 0);
            }
        }
        // C layout: col = lane&15 (=d offset), row = (lane>>4)*4 + reg (=px offset)
        const int d = w * 16 + lr;
        const float s = scalef[d], bb = biasf[d];
#pragma unroll
        for (int m = 0; m < 4; ++m)
#pragma unroll
            for (int r = 0; r < 4; ++r)
                hS[(m * 16 + lq * 4 + r) * 69 + d] = fmaxf(fmaf(acc[m][r], s, bb), 0.f);
    }
    __syncthreads();

    // ---- phase 2: kern = h @ w2 + b2 (VALU; thread = (px, d-quarter)) ----
    {
        const int px = t >> 2, dq = t & 3;
        float kp[KK];
#pragma unroll
        for (int k = 0; k < KK; ++k) kp[k] = 0.f;

        const float* hrow = hS + px * 69 + dq * 16;
#pragma unroll
        for (int e = 0; e < 16; ++e) {
            float hv = hrow[e];
            const float4* wr = (const float4*)(w2p + (dq * 16 + e) * 12);
            float4 wa = wr[0], wb = wr[1], wc = wr[2];
            kp[0] = fmaf(hv, wa.x, kp[0]);
            kp[1] = fmaf(hv, wa.y, kp[1]);
            kp[2] = fmaf(hv, wa.z, kp[2]);
            kp[3] = fmaf(hv, wa.w, kp[3]);
            kp[4] = fmaf(hv, wb.x, kp[4]);
            kp[5] = fmaf(hv, wb.y, kp[5]);
            kp[6] = fmaf(hv, wb.z, kp[6]);
            kp[7] = fmaf(hv, wb.w, kp[7]);
            kp[8] = fmaf(hv, wc.x, kp[8]);
        }
#pragma unroll
        for (int k = 0; k < KK; ++k) {
            kp[k] += __shfl_xor(kp[k], 1, 64);
            kp[k] += __shfl_xor(kp[k], 2, 64);
        }
        if (dq == 0) {
            float* kr = kout + (size_t)(p0 + px) * KK;
#pragma unroll
            for (int k = 0; k < KK; ++k) {
                float kv = kp[k] + b2f[k];
                kS[px * 13 + k] = kv;
                kr[k] = kv;
            }
        }
    }
    __syncthreads();

    // ---- phase 3: involution; thread = (ps, c4): pixels {ps+16f}, channels c4*4..+3 ----
    // store instr f covers out[p0*64 + f*1024 + t*4 ..] -> contiguous 1KB per instr
    {
        const int ps = t >> 4, c4 = t & 15;
        const int b = p0 >> 14;
        const int i = (p0 >> 7) & 127;       // uniform: block never spans an image row
        const int j0 = p0 & 127;

        float kf[4][KK];
#pragma unroll
        for (int f = 0; f < 4; ++f)
#pragma unroll
            for (int k = 0; k < KK; ++k)
                kf[f][k] = kS[(16 * f + ps) * 13 + k];

        float4 acc[4];
#pragma unroll
        for (int f = 0; f < 4; ++f) acc[f] = make_float4(0.f, 0.f, 0.f, 0.f);

#pragma unroll
        for (int ti = -1; ti <= 1; ++ti) {
            int ii = i + ti;
            if (ii < 0 || ii >= HH) continue;            // wave-uniform skip (zero-pad)
            const float* rowp = x + ((size_t)b * HH + ii) * WW * CC;
#pragma unroll
            for (int tj = -1; tj <= 1; ++tj) {
                const int tap = (ti + 1) * 3 + (tj + 1);
#pragma unroll
                for (int f = 0; f < 4; ++f) {
                    int jj = j0 + 16 * f + ps + tj;
                    bool valid = (jj >= 0) && (jj < WW);
                    float kv = valid ? kf[f][tap] : 0.f;
                    int jjc = min(max(jj, 0), WW - 1);
                    float4 v = *(const float4*)(rowp + jjc * CC + c4 * 4);
                    acc[f].x = fmaf(kv, v.x, acc[f].x);
                    acc[f].y = fmaf(kv, v.y, acc[f].y);
                    acc[f].z = fmaf(kv, v.z, acc[f].z);
                    acc[f].w = fmaf(kv, v.w, acc[f].w);
                }
            }
        }
#pragma unroll
        for (int f = 0; f < 4; ++f)
            *(float4*)(out + (size_t)(p0 + 16 * f + ps) * CC + c4 * 4) = acc[f];
    }
}

extern "C" void kernel_launch(void* const* d_in, const int* in_sizes, int n_in,
                              void* d_out, int out_size, void* d_ws, size_t ws_size,
                              hipStream_t stream) {
    const float* x       = (const float*)d_in[0];
    const float* w1      = (const float*)d_in[1];
    const float* b1      = (const float*)d_in[2];
    const float* gamma   = (const float*)d_in[3];
    const float* beta    = (const float*)d_in[4];
    const float* bn_mean = (const float*)d_in[5];
    const float* bn_var  = (const float*)d_in[6];
    const float* w2      = (const float*)d_in[7];
    const float* b2      = (const float*)d_in[8];

    ushort_t* w1b = (ushort_t*)d_ws;                 // 4096 ushort = 8192 B
    float* w2p    = (float*)d_ws + 2048;             // 768
    float* scalef = w2p + CC * 12;                   // 64
    float* biasf  = scalef + CC;                     // 64
    float* b2f    = biasf + CC;                      // 9

    float* out  = (float*)d_out;
    float* kout = out + (size_t)NPIX * CC;

    hipLaunchKernelGGL(setup_kernel, dim3(20), dim3(256), 0, stream,
                       w1, b1, gamma, beta, bn_mean, bn_var, w2, b2,
                       w1b, w2p, scalef, biasf, b2f);

    hipLaunchKernelGGL(invol_kernel, dim3(NPIX / 64), dim3(256), 0, stream,
                       x, w1b, w2p, scalef, biasf, b2f, out, kout);
}